// Round 1
// baseline (695.323 us; speedup 1.0000x reference)
//
#include <hip/hip_runtime.h>
#include <math.h>

#define IN_F 256
#define OUT_F 128
#define HEADS 4
#define HF 512   // HEADS*OUT_F

__device__ __forceinline__ void atomicMaxF(float* addr, float val) {
    // works for mixed signs; init pattern 0xFFFFFFFF (-NaN) always loses
    if (val >= 0.f) atomicMax((int*)addr, __float_as_int(val));
    else            atomicMin((unsigned int*)addr, __float_as_uint(val));
}

// ---------------- GEMM: C[M,N] = A[M,K] @ B[K,N] (+ bias[N]) ----------------
__global__ __launch_bounds__(256) void gemm_bias(
    const float* __restrict__ A, const float* __restrict__ B,
    const float* __restrict__ bias, float* __restrict__ C,
    int M, int N, int K) {
    const int BM = 64, BN = 64, BK = 32;
    __shared__ float As[BK][BM + 1];
    __shared__ float Bs[BK][BN + 1];
    int tid = threadIdx.x;
    int tr = tid >> 4, tc = tid & 15;          // 16x16 thread grid, 4x4 micro
    int brow = blockIdx.y * BM, bcol = blockIdx.x * BN;
    float acc[4][4] = {};
    for (int k0 = 0; k0 < K; k0 += BK) {
        #pragma unroll
        for (int t = tid; t < BM * BK; t += 256) {
            int m = t >> 5, k = t & 31;
            As[k][m] = A[(size_t)(brow + m) * K + k0 + k];
        }
        #pragma unroll
        for (int t = tid; t < BK * BN; t += 256) {
            int k = t >> 6, n = t & 63;
            Bs[k][n] = B[(size_t)(k0 + k) * N + bcol + n];
        }
        __syncthreads();
        #pragma unroll
        for (int k = 0; k < BK; ++k) {
            float a[4], b[4];
            #pragma unroll
            for (int i = 0; i < 4; i++) a[i] = As[k][tr * 4 + i];
            #pragma unroll
            for (int j = 0; j < 4; j++) b[j] = Bs[k][tc * 4 + j];
            #pragma unroll
            for (int i = 0; i < 4; i++)
                #pragma unroll
                for (int j = 0; j < 4; j++)
                    acc[i][j] = fmaf(a[i], b[j], acc[i][j]);
        }
        __syncthreads();
    }
    #pragma unroll
    for (int i = 0; i < 4; i++) {
        int r = brow + tr * 4 + i;
        #pragma unroll
        for (int j = 0; j < 4; j++) {
            int c = bcol + tc * 4 + j;
            float v = acc[i][j];
            if (bias) v += bias[c];
            C[(size_t)r * N + c] = v;
        }
    }
}

// ---------------- GAT edge pipeline ----------------
// one wave per edge: score[e,h] = att[h] . leaky0.2(xl[src,h,:] + xr[dst,h,:])
__global__ __launch_bounds__(256) void edge_score_kernel(
    const float* __restrict__ xl, const float* __restrict__ xr,
    const int* __restrict__ ei, const float* __restrict__ att,
    float* __restrict__ score, float* __restrict__ mbuf, int E, int N) {
    int wid = (blockIdx.x * 256 + threadIdx.x) >> 6;
    int lane = threadIdx.x & 63;
    int Etot = E + N;
    if (wid >= Etot) return;
    int src, dst;
    if (wid < E) { src = ei[wid]; dst = ei[E + wid]; }
    else         { src = dst = wid - E; }
    const float* xls = xl + (size_t)src * HF;
    const float* xrd = xr + (size_t)dst * HF;
    #pragma unroll
    for (int h = 0; h < HEADS; ++h) {
        float e0 = xls[h * 128 + lane]      + xrd[h * 128 + lane];
        float e1 = xls[h * 128 + lane + 64] + xrd[h * 128 + lane + 64];
        e0 = e0 > 0.f ? e0 : 0.2f * e0;
        e1 = e1 > 0.f ? e1 : 0.2f * e1;
        float s = e0 * att[h * 128 + lane] + e1 * att[h * 128 + lane + 64];
        #pragma unroll
        for (int off = 32; off; off >>= 1) s += __shfl_xor(s, off);
        if (lane == 0) {
            score[(size_t)wid * HEADS + h] = s;
            atomicMaxF(&mbuf[dst * HEADS + h], s);
        }
    }
}

__global__ __launch_bounds__(256) void edge_exp_kernel(
    const int* __restrict__ ei, const float* __restrict__ mbuf,
    float* __restrict__ score, float* __restrict__ denom, int E, int N) {
    int idx = blockIdx.x * 256 + threadIdx.x;
    int Etot = E + N;
    if (idx >= Etot * HEADS) return;
    int e = idx >> 2, h = idx & 3;
    int dst = (e < E) ? ei[E + e] : (e - E);
    float ex = expf(score[idx] - mbuf[dst * HEADS + h]);
    score[idx] = ex;
    atomicAdd(&denom[dst * HEADS + h], ex);
}

// one wave per edge: hgat[dst,f] += sum_h 0.25*alpha[h]*xl[src,h,f]
__global__ __launch_bounds__(256) void edge_agg_kernel(
    const float* __restrict__ xl, const int* __restrict__ ei,
    const float* __restrict__ score, const float* __restrict__ denom,
    float* __restrict__ hgat, int E, int N) {
    int wid = (blockIdx.x * 256 + threadIdx.x) >> 6;
    int lane = threadIdx.x & 63;
    int Etot = E + N;
    if (wid >= Etot) return;
    int src, dst;
    if (wid < E) { src = ei[wid]; dst = ei[E + wid]; }
    else         { src = dst = wid - E; }
    float alpha[HEADS];
    #pragma unroll
    for (int h = 0; h < HEADS; ++h)
        alpha[h] = 0.25f * score[(size_t)wid * HEADS + h] / denom[dst * HEADS + h];
    const float* xls = xl + (size_t)src * HF;
    #pragma unroll
    for (int half = 0; half < 2; ++half) {
        int f = lane + half * 64;
        float c = 0.f;
        #pragma unroll
        for (int h = 0; h < HEADS; ++h) c = fmaf(alpha[h], xls[h * 128 + f], c);
        atomicAdd(&hgat[(size_t)dst * 128 + f], c);
    }
}

// ---------------- conv branch ----------------
// conv_W[o][i][k] (128,128,7) -> Wt[k][i][o] for coalesced loads
__global__ void transpose_w_kernel(const float* __restrict__ W, float* __restrict__ Wt) {
    int idx = blockIdx.x * 256 + threadIdx.x;
    if (idx >= 128 * 128 * 7) return;
    int o = idx / 896, rem = idx % 896, i = rem / 7, k = rem % 7;
    Wt[((size_t)k * 128 + i) * 128 + o] = W[idx];
}

// block: (batch b, 16-wide L chunk). hc[b,l,o] = sum_{k,i} W[o,i,k]*xc[b,l+k-3,i]
__global__ __launch_bounds__(256) void conv1d_kernel(
    const float* __restrict__ xc, const float* __restrict__ Wt,
    float* __restrict__ hc) {
    __shared__ float lds[128 * 24];   // transposed: lds[i*24 + r], r = local row
    int b = blockIdx.y;
    int l0 = blockIdx.x * 16;
    int tid = threadIdx.x;
    int i = tid & 127, r0 = tid >> 7;
    for (int r = r0; r < 22; r += 2) {
        int l = l0 - 3 + r;
        float v = (l >= 0 && l < 512) ? xc[((size_t)b * 512 + l) * 128 + i] : 0.f;
        lds[i * 24 + r] = v;
    }
    __syncthreads();
    int o = tid & 127, lp = tid >> 7;    // thread owns (o, l = lp+2j) j=0..7
    float acc[8] = {};
    for (int ii = 0; ii < 128; ++ii) {
        float xv[21];
        #pragma unroll
        for (int r = 0; r < 21; ++r) xv[r] = lds[ii * 24 + lp + r];
        #pragma unroll
        for (int k = 0; k < 7; ++k) {
            float w = Wt[((size_t)k * 128 + ii) * 128 + o];
            #pragma unroll
            for (int j = 0; j < 8; ++j)
                acc[j] = fmaf(w, xv[2 * j + k], acc[j]);
        }
    }
    #pragma unroll
    for (int j = 0; j < 8; ++j) {
        int l = l0 + lp + 2 * j;
        hc[((size_t)b * 512 + l) * 128 + o] = acc[j];
    }
}

// ---------------- layernorm epilogues ----------------
// in-place: row = LN(act(row + bias)) ; act = leaky(slope) (slope=0 -> relu)
__global__ __launch_bounds__(256) void post_ln_kernel(
    float* __restrict__ buf, const float* __restrict__ bias,
    const float* __restrict__ gamma, const float* __restrict__ beta,
    float slope, int N) {
    int wid = (blockIdx.x * 256 + threadIdx.x) >> 6;
    int lane = threadIdx.x & 63;
    if (wid >= N) return;
    float* row = buf + (size_t)wid * 128;
    float v0 = row[lane], v1 = row[lane + 64];
    if (bias) { v0 += bias[lane]; v1 += bias[lane + 64]; }
    v0 = v0 > 0.f ? v0 : slope * v0;
    v1 = v1 > 0.f ? v1 : slope * v1;
    float s = v0 + v1;
    #pragma unroll
    for (int off = 32; off; off >>= 1) s += __shfl_xor(s, off);
    float mu = s * (1.f / 128.f);
    float d0 = v0 - mu, d1 = v1 - mu;
    float vs = d0 * d0 + d1 * d1;
    #pragma unroll
    for (int off = 32; off; off >>= 1) vs += __shfl_xor(vs, off);
    float inv = rsqrtf(vs * (1.f / 128.f) + 1e-5f);
    row[lane]      = d0 * inv * gamma[lane]      + beta[lane];
    row[lane + 64] = d1 * inv * gamma[lane + 64] + beta[lane + 64];
}

__global__ __launch_bounds__(256) void fuse_ln_kernel(
    const float* __restrict__ a, const float* __restrict__ b2,
    const float* __restrict__ c, const float* __restrict__ gamma,
    const float* __restrict__ beta, float* __restrict__ out, int N) {
    int wid = (blockIdx.x * 256 + threadIdx.x) >> 6;
    int lane = threadIdx.x & 63;
    if (wid >= N) return;
    size_t base = (size_t)wid * 128;
    float v0 = a[base + lane]      + b2[base + lane]      + c[base + lane];
    float v1 = a[base + lane + 64] + b2[base + lane + 64] + c[base + lane + 64];
    float s = v0 + v1;
    #pragma unroll
    for (int off = 32; off; off >>= 1) s += __shfl_xor(s, off);
    float mu = s * (1.f / 128.f);
    float d0 = v0 - mu, d1 = v1 - mu;
    float vs = d0 * d0 + d1 * d1;
    #pragma unroll
    for (int off = 32; off; off >>= 1) vs += __shfl_xor(vs, off);
    float inv = rsqrtf(vs * (1.f / 128.f) + 1e-5f);
    out[base + lane]      = d0 * inv * gamma[lane]      + beta[lane];
    out[base + lane + 64] = d1 * inv * gamma[lane + 64] + beta[lane + 64];
}

extern "C" void kernel_launch(void* const* d_in, const int* in_sizes, int n_in,
                              void* d_out, int out_size, void* d_ws, size_t ws_size,
                              hipStream_t stream) {
    const float* x         = (const float*)d_in[0];
    const int*   ei        = (const int*)d_in[1];
    const float* W_l       = (const float*)d_in[2];
    const float* W_r       = (const float*)d_in[3];
    const float* att       = (const float*)d_in[4];
    const float* gat_bias  = (const float*)d_in[5];
    const float* gat_gamma = (const float*)d_in[6];
    const float* gat_beta  = (const float*)d_in[7];
    const float* cnn_W     = (const float*)d_in[8];
    const float* cnn_b     = (const float*)d_in[9];
    const float* conv_W    = (const float*)d_in[10];
    const float* conv_b    = (const float*)d_in[11];
    const float* cnn_gamma = (const float*)d_in[12];
    const float* cnn_beta  = (const float*)d_in[13];
    const float* res_W     = (const float*)d_in[14];
    const float* res_b     = (const float*)d_in[15];
    const float* fuse_gamma= (const float*)d_in[16];
    const float* fuse_beta = (const float*)d_in[17];

    int N = in_sizes[0] / IN_F;   // 16384
    int E = in_sizes[1] / 2;      // 262144
    int Etot = E + N;

    // workspace layout (floats). hc/res/xc alias the xr buffer: xr's last
    // read is edge_score, and those three are written strictly after it.
    char* ws = (char*)d_ws;
    float* xl    = (float*)ws;                               // N*512
    float* xr    = (float*)(ws + (size_t)N * HF * 4);        // N*512
    float* res   = xr;                                       // N*128 (after edge_score)
    float* hc    = xr + (size_t)N * 128;                     // N*128
    float* xc    = xr + (size_t)N * 256;                     // N*128
    float* score = (float*)(ws + (size_t)2 * N * HF * 4);    // Etot*4
    float* mbuf  = score + (size_t)Etot * HEADS;             // N*4
    float* denom = mbuf  + (size_t)N * HEADS;                // N*4
    float* hgat  = denom + (size_t)N * HEADS;                // N*128
    float* Wt    = hgat  + (size_t)N * 128;                  // 128*128*7

    hipMemsetAsync(mbuf,  0xFF, (size_t)N * HEADS * 4, stream);  // -NaN sentinel
    hipMemsetAsync(denom, 0,    (size_t)N * HEADS * 4, stream);
    hipMemsetAsync(hgat,  0,    (size_t)N * 128 * 4,   stream);

    dim3 blk(256);
    // projections
    gemm_bias<<<dim3(HF / 64, N / 64), blk, 0, stream>>>(x, W_l, nullptr, xl, N, HF, IN_F);
    gemm_bias<<<dim3(HF / 64, N / 64), blk, 0, stream>>>(x, W_r, nullptr, xr, N, HF, IN_F);
    transpose_w_kernel<<<(128 * 128 * 7 + 255) / 256, blk, 0, stream>>>(conv_W, Wt);

    // GAT pipeline
    int wblocks = (Etot + 3) / 4;
    edge_score_kernel<<<wblocks, blk, 0, stream>>>(xl, xr, ei, att, score, mbuf, E, N);
    edge_exp_kernel<<<(Etot * HEADS + 255) / 256, blk, 0, stream>>>(ei, mbuf, score, denom, E, N);
    edge_agg_kernel<<<wblocks, blk, 0, stream>>>(xl, ei, score, denom, hgat, E, N);

    // CNN + residual branch (xc/res write into xr region: after edge_score)
    gemm_bias<<<dim3(128 / 64, N / 64), blk, 0, stream>>>(x, cnn_W, cnn_b, xc, N, 128, IN_F);
    gemm_bias<<<dim3(128 / 64, N / 64), blk, 0, stream>>>(x, res_W, res_b, res, N, 128, IN_F);
    conv1d_kernel<<<dim3(512 / 16, N / 512), blk, 0, stream>>>(xc, Wt, hc);

    // epilogues
    post_ln_kernel<<<(N + 3) / 4, blk, 0, stream>>>(hgat, gat_bias, gat_gamma, gat_beta, 0.01f, N);
    post_ln_kernel<<<(N + 3) / 4, blk, 0, stream>>>(hc, conv_b, cnn_gamma, cnn_beta, 0.0f, N);
    fuse_ln_kernel<<<(N + 3) / 4, blk, 0, stream>>>(hgat, hc, res, fuse_gamma, fuse_beta,
                                                    (float*)d_out, N);
}